// Round 1
// baseline (123.619 us; speedup 1.0000x reference)
//
#include <hip/hip_runtime.h>
#include <stdint.h>

// Problem constants (fixed by reference)
#define N_IMG   16
#define C_IN    256
#define H_IN    32
#define W_IN    32
#define OH      30
#define OW      30
#define K_SEL   1152                  // C*KH*KW/2
#define OUTC    512
#define RY_TOT  (N_IMG * OH)          // 480 (n,y) rows
#define M_HAT   (RY_TOT * 32)         // 15360 = padded M (ow 30 -> 32)
#define X_ELEMS (N_IMG * C_IN * H_IN * W_IN)   // 4194304
#define OUT_SP  (OH * OW)             // 900

typedef float f32x4  __attribute__((ext_vector_type(4)));
typedef short bf16x8 __attribute__((ext_vector_type(8)));   // 8 bf16 = 4 VGPRs (guide §3)

__device__ __forceinline__ unsigned short f2bf(float f) {   // fp32 -> bf16 RNE
    unsigned int u = __float_as_uint(f);
    u += 0x7FFFu + ((u >> 16) & 1u);
    return (unsigned short)(u >> 16);
}

// async global->LDS, 16B/lane. LDS dst must be wave-uniform base; HW adds lane*16.
__device__ __forceinline__ void gl_lds16(const void* g, void* lds) {
    __builtin_amdgcn_global_load_lds(
        (const __attribute__((address_space(1))) unsigned int*)g,
        (__attribute__((address_space(3))) unsigned int*)lds,
        16, 0, 0);
}

// ---------------------------------------------------------------------------
// Prepass 1: decode idx -> gather offsets koff[k] = c*1024 + i*32 + j
// ---------------------------------------------------------------------------
__global__ void koff_kernel(const int* __restrict__ idx, int* __restrict__ koff) {
    int k = blockIdx.x * 256 + threadIdx.x;
    if (k < K_SEL) {
        int v   = idx[k];
        int c   = v / 9;
        int rem = v - c * 9;
        int i   = rem / 3;
        int j   = rem - i * 3;
        koff[k] = c * (H_IN * W_IN) + i * W_IN + j;
    }
}

// ---------------------------------------------------------------------------
// Prepass 2: weight (K_SEL x OUTC fp32) -> wT (OUTC x K_SEL bf16), k-contiguous
// ---------------------------------------------------------------------------
__global__ void wt_kernel(const float* __restrict__ w, unsigned short* __restrict__ wT) {
    int id = blockIdx.x * 256 + threadIdx.x;       // grid covers 512*1152 exactly
    int o  = id / K_SEL;
    int s  = id - o * K_SEL;
    wT[id] = f2bf(w[s * OUTC + o]);                // writes coalesced; reads L2-resident
}

// ---------------------------------------------------------------------------
// Prepass 3: materialize bf16 im2col  Amat[m_hat][k], m_hat=(n*30+y)*32+xw
// Block = one ry (n,y) row x 128 k. LDS transpose: gather reads coalesced
// along xw, stores coalesced along k.
// ---------------------------------------------------------------------------
__global__ void amat_kernel(const float* __restrict__ x, const int* __restrict__ koff,
                            unsigned short* __restrict__ Am) {
    __shared__ float tile[32 * 129];               // [xw][k], +1 pad: conflict-free
    const int rb = blockIdx.x;                     // ry in [0,480)
    const int kb = blockIdx.y;                     // k-chunk in [0,9)
    const int t  = threadIdx.x;
    const int n  = rb / OH;
    const int y  = rb - n * OH;
    const int base = n * (C_IN * H_IN * W_IN) + y * W_IN;

    const int xw = t & 31;
    const int kq = t >> 5;                          // 0..7
#pragma unroll
    for (int r = 0; r < 16; ++r) {
        int kl = kq * 16 + r;                       // 0..127
        int g  = base + koff[kb * 128 + kl] + xw;   // lanes 0..31: 128B coalesced
        g = min(g, X_ELEMS - 1);                    // xw>=30 pad rows: clamp (masked later)
        tile[xw * 129 + kl] = x[g];
    }
    __syncthreads();

    const int kp = t & 63;                          // k-pair 0..63
    const int xg = t >> 6;                          // 0..3
#pragma unroll
    for (int r = 0; r < 8; ++r) {
        int xw2 = r * 4 + xg;
        float f0 = tile[xw2 * 129 + 2 * kp];
        float f1 = tile[xw2 * 129 + 2 * kp + 1];
        unsigned int pk = (unsigned int)f2bf(f0) | ((unsigned int)f2bf(f1) << 16);
        size_t off = (size_t)(rb * 32 + xw2) * K_SEL + kb * 128 + 2 * kp;
        *reinterpret_cast<unsigned int*>(&Am[off]) = pk;   // 64 lanes x 4B contiguous
    }
}

// ---------------------------------------------------------------------------
// GEMM: C[o][m_hat] = wT(512 x 1152) x Amat^T(1152 x 15360), m97 structure.
// Block 256 = 4 waves, tile 128(o) x 128(m), BK=32, 16x16x32 bf16 MFMA.
// Output orientation: MFMA col (=lane&15) is the spatial dim -> coalesced stores.
// ---------------------------------------------------------------------------
__global__ __launch_bounds__(256) void gemm_kernel(const unsigned short* __restrict__ wT,
                                                   const unsigned short* __restrict__ Am,
                                                   float* __restrict__ out) {
    __shared__ __align__(16) unsigned short As[128 * 32];  // rows = o, k-contig
    __shared__ __align__(16) unsigned short Bs[128 * 32];  // rows = m_hat, k-contig

    const int t    = threadIdx.x;
    const int wave = t >> 6;
    const int lane = t & 63;
    const int quad = lane >> 4;
    const int lo   = lane & 15;

    const int ot = blockIdx.x & 3;                 // 4 o-tiles
    const int mt = blockIdx.x >> 2;                // 120 m-tiles
    const int oBase = ot * 128;
    const int mBase = mt * 128;
    const int wo = (wave & 1) * 64;                // wave quadrant
    const int wm = (wave >> 1) * 64;

    f32x4 acc[4][4] = {};

    // staging coords: lane L -> row L/4 (of 16), k-sub (L%4)*8; LDS gets lane*16B
    const int lrow = lane >> 2;
    const int lks  = (lane & 3) * 8;
    const unsigned short* wrow0 = wT + (size_t)(oBase + wave * 16 + lrow) * K_SEL + lks;
    const unsigned short* wrow1 = wrow0 + (size_t)64 * K_SEL;
    const unsigned short* arow0 = Am + (size_t)(mBase + wave * 16 + lrow) * K_SEL + lks;
    const unsigned short* arow1 = arow0 + (size_t)64 * K_SEL;
    unsigned short* lA0 = &As[(wave * 16) * 32];
    unsigned short* lA1 = &As[(64 + wave * 16) * 32];
    unsigned short* lB0 = &Bs[(wave * 16) * 32];
    unsigned short* lB1 = &Bs[(64 + wave * 16) * 32];

    for (int kt = 0; kt < K_SEL / 32; ++kt) {      // 36 iters
        const int k0 = kt * 32;
        gl_lds16(wrow0 + k0, lA0);
        gl_lds16(wrow1 + k0, lA1);
        gl_lds16(arow0 + k0, lB0);
        gl_lds16(arow1 + k0, lB1);
        __syncthreads();                           // drains vmcnt before barrier

        bf16x8 a[4], b[4];
#pragma unroll
        for (int ms = 0; ms < 4; ++ms)
            a[ms] = *(const bf16x8*)&As[(wo + ms * 16 + lo) * 32 + quad * 8];
#pragma unroll
        for (int ns = 0; ns < 4; ++ns)
            b[ns] = *(const bf16x8*)&Bs[(wm + ns * 16 + lo) * 32 + quad * 8];
#pragma unroll
        for (int ms = 0; ms < 4; ++ms)
#pragma unroll
            for (int ns = 0; ns < 4; ++ns)
                acc[ms][ns] = __builtin_amdgcn_mfma_f32_16x16x32_bf16(
                    a[ms], b[ns], acc[ms][ns], 0, 0, 0);
        __syncthreads();                           // LDS consumed before next stage
    }

    // Epilogue: D row = o (quad*4+reg), col = m_hat (lane&15). Mask padded xw.
#pragma unroll
    for (int ns = 0; ns < 4; ++ns) {
        const int mh = mBase + wm + ns * 16 + lo;
        const int xw = mh & 31;
        const unsigned int ry = (unsigned int)(mh >> 5);
        const unsigned int n  = ry / 30u;
        const unsigned int yy = ry - n * 30u;
        if (xw < OW) {
            const size_t ob = (size_t)n * (OUTC * OUT_SP) + (size_t)yy * OW + xw;
#pragma unroll
            for (int ms = 0; ms < 4; ++ms) {
                const int o0 = oBase + wo + ms * 16 + quad * 4;
#pragma unroll
                for (int r = 0; r < 4; ++r)
                    out[ob + (size_t)(o0 + r) * OUT_SP] = acc[ms][ns][r];
            }
        }
    }
}

// ---------------------------------------------------------------------------
extern "C" void kernel_launch(void* const* d_in, const int* in_sizes, int n_in,
                              void* d_out, int out_size, void* d_ws, size_t ws_size,
                              hipStream_t stream) {
    const float* x   = (const float*)d_in[0];
    const float* w   = (const float*)d_in[1];
    const int*   idx = (const int*)d_in[2];
    float*       out = (float*)d_out;

    // ws layout: koff (4608B) | wT bf16 (1179648B) | Amat bf16 (35389440B) ~= 36.6MB
    char* ws = (char*)d_ws;
    int*            koff = (int*)ws;
    unsigned short* wT   = (unsigned short*)(ws + 4608);
    unsigned short* Am   = (unsigned short*)(ws + 4608 + 1179648);

    koff_kernel<<<dim3(5), dim3(256), 0, stream>>>(idx, koff);
    wt_kernel<<<dim3((OUTC * K_SEL) / 256), dim3(256), 0, stream>>>(w, wT);
    amat_kernel<<<dim3(RY_TOT, K_SEL / 128), dim3(256), 0, stream>>>(x, koff, Am);
    gemm_kernel<<<dim3((M_HAT / 128) * (OUTC / 128)), dim3(256), 0, stream>>>(wT, Am, out);
}